// Round 1
// baseline (710.443 us; speedup 1.0000x reference)
//
#include <hip/hip_runtime.h>
#include <hip/hip_bf16.h>

// Problem constants (HierarchicalFeaturesExtractor): B=64, S=512, E=256, D=512
#define EDIM 256
#define SDIM 512
#define BDIM 64
#define DDIM 512

// ws layout (in floats):
//   G_int [512][1536]  @ 0          (interior combined weights, delta=-2..3)
//   G0    [512][1024]  @ 786432     (s=0 weights, delta=0..3)
//   G1    [512][1280]  @ 1310720    (s=1 weights, delta=-1..3)
//   bias_int [512]     @ 1966080
//   bias0    [512]     @ 1966592
//   bias1    [512]     @ 1967104
#define OFF_GINT 0
#define OFF_G0   786432
#define OFF_G1   1310720
#define OFF_BI   1966080
#define OFF_B0   1966592
#define OFF_B1   1967104

// Build combined conv weights.
// Derivation: out[b,s] = unigram + [s<256] * (F2[s] + F3[s-1]+F3[s] + F4[s-2]+F4[s-1]+F4[s])
// where Fn[p] = bn + sum_k x[p+k] . Wn[:,:,k]. Grouping by absolute offset delta = (p+k)-s:
//   interior (2<=s<256):
//     d=-2: W4_0
//     d=-1: W3_0 + W4_0 + W4_1
//     d= 0: W1 + W2_0 + W3_0 + W3_1 + W4_0 + W4_1 + W4_2
//     d= 1: W2_1 + W3_1 + W3_2 + W4_1 + W4_2 + W4_3
//     d= 2: W3_2 + W4_2 + W4_3
//     d= 3: W4_3
//     bias = b1 + b2 + 2*b3 + 3*b4
//   s=0 (only F2[0],F3[0],F4[0]):  d0: W1+W2_0+W3_0+W4_0; d1: W2_1+W3_1+W4_1; d2: W3_2+W4_2; d3: W4_3
//     bias = b1+b2+b3+b4
//   s=1 (drop F4[-1]): d-1: W3_0+W4_0; d0: W1+W2_0+W3_0+W3_1+W4_0+W4_1;
//     d1: W2_1+W3_1+W3_2+W4_1+W4_2; d2: W3_2+W4_2+W4_3; d3: W4_3
//     bias = b1+b2+2*b3+2*b4
__global__ void prep_weights(const float* __restrict__ W1, const float* __restrict__ b1,
                             const float* __restrict__ W2, const float* __restrict__ b2,
                             const float* __restrict__ W3, const float* __restrict__ b3,
                             const float* __restrict__ W4, const float* __restrict__ b4,
                             float* __restrict__ ws)
{
    const int d = blockIdx.x;    // 0..511
    const int e = threadIdx.x;   // 0..255
    const int de = d * EDIM + e;

    const float w1  = W1[de];
    const float w20 = W2[de * 2 + 0], w21 = W2[de * 2 + 1];
    const float w30 = W3[de * 3 + 0], w31 = W3[de * 3 + 1], w32 = W3[de * 3 + 2];
    const float w40 = W4[de * 4 + 0], w41 = W4[de * 4 + 1], w42 = W4[de * 4 + 2], w43 = W4[de * 4 + 3];

    float* Gi = ws + OFF_GINT + (size_t)d * 1536;
    Gi[0 * EDIM + e] = w40;
    Gi[1 * EDIM + e] = w30 + w40 + w41;
    Gi[2 * EDIM + e] = w1 + w20 + w30 + w31 + w40 + w41 + w42;
    Gi[3 * EDIM + e] = w21 + w31 + w32 + w41 + w42 + w43;
    Gi[4 * EDIM + e] = w32 + w42 + w43;
    Gi[5 * EDIM + e] = w43;

    float* G0 = ws + OFF_G0 + (size_t)d * 1024;
    G0[0 * EDIM + e] = w1 + w20 + w30 + w40;
    G0[1 * EDIM + e] = w21 + w31 + w41;
    G0[2 * EDIM + e] = w32 + w42;
    G0[3 * EDIM + e] = w43;

    float* G1 = ws + OFF_G1 + (size_t)d * 1280;
    G1[0 * EDIM + e] = w30 + w40;
    G1[1 * EDIM + e] = w1 + w20 + w30 + w31 + w40 + w41;
    G1[2 * EDIM + e] = w21 + w31 + w32 + w41 + w42;
    G1[3 * EDIM + e] = w32 + w42 + w43;
    G1[4 * EDIM + e] = w43;

    if (e == 0) {
        ws[OFF_BI + d] = b1[d] + b2[d] + 2.0f * b3[d] + 3.0f * b4[d];
        ws[OFF_B0 + d] = b1[d] + b2[d] + b3[d] + b4[d];
        ws[OFF_B1 + d] = b1[d] + b2[d] + 2.0f * b3[d] + 2.0f * b4[d];
    }
}

// Generic "rows-of-x times weight-matrix" GEMM.
// Row r -> (b = r / s_cnt, s = s_lo + r % s_cnt). A-row = x[b, s+dlo, :] .. (K contiguous floats).
// Wm is [DDIM, K] row-major. out[b, s, :] = A-row . Wm^T + bias.
// Tile: 64x64, BK=16, 256 threads, 4x4 micro-tile per thread.
#define BM 64
#define BN 64
#define BK 16

__global__ __launch_bounds__(256) void gemm_rows(
    const float* __restrict__ X, const float* __restrict__ Wm,
    const float* __restrict__ bias, float* __restrict__ out,
    int s_lo, int s_cnt, int K, int dlo)
{
    __shared__ __align__(16) float As[BK][BM + 4];
    __shared__ __align__(16) float Bs[BK][BN + 4];

    const int tid  = threadIdx.x;
    const int row0 = blockIdx.x * BM;
    const int col0 = blockIdx.y * BN;

    // Loading assignment: each thread loads one float4 of A and one of B per K-tile.
    const int lr = tid >> 2;          // 0..63: row (A) / col (B) within tile
    const int lk = (tid & 3) << 2;    // 0,4,8,12: k offset of the float4

    const int r = row0 + lr;
    const int b = r / s_cnt;
    const int s = s_lo + (r - b * s_cnt);
    const float* arow = X + ((size_t)(b * SDIM + s + dlo)) * EDIM;
    const float* brow = Wm + (size_t)(col0 + lr) * K;

    const int ty = tid >> 4;   // 0..15 -> rows 4*ty..4*ty+3
    const int tx = tid & 15;   // 0..15 -> cols 4*tx..4*tx+3

    float acc[4][4] = {{0.f}};

    for (int k0 = 0; k0 < K; k0 += BK) {
        const float4 av = *(const float4*)(arow + k0 + lk);
        const float4 bv = *(const float4*)(brow + k0 + lk);
        __syncthreads();
        As[lk + 0][lr] = av.x; As[lk + 1][lr] = av.y; As[lk + 2][lr] = av.z; As[lk + 3][lr] = av.w;
        Bs[lk + 0][lr] = bv.x; Bs[lk + 1][lr] = bv.y; Bs[lk + 2][lr] = bv.z; Bs[lk + 3][lr] = bv.w;
        __syncthreads();
#pragma unroll
        for (int k = 0; k < BK; ++k) {
            const float4 a  = *(const float4*)&As[k][ty << 2];
            const float4 bq = *(const float4*)&Bs[k][tx << 2];
            acc[0][0] += a.x * bq.x; acc[0][1] += a.x * bq.y; acc[0][2] += a.x * bq.z; acc[0][3] += a.x * bq.w;
            acc[1][0] += a.y * bq.x; acc[1][1] += a.y * bq.y; acc[1][2] += a.y * bq.z; acc[1][3] += a.y * bq.w;
            acc[2][0] += a.z * bq.x; acc[2][1] += a.z * bq.y; acc[2][2] += a.z * bq.z; acc[2][3] += a.z * bq.w;
            acc[3][0] += a.w * bq.x; acc[3][1] += a.w * bq.y; acc[3][2] += a.w * bq.z; acc[3][3] += a.w * bq.w;
        }
    }

    const float4 bb = *(const float4*)&bias[col0 + (tx << 2)];
#pragma unroll
    for (int i = 0; i < 4; ++i) {
        const int rr = row0 + (ty << 2) + i;
        const int b2 = rr / s_cnt;
        const int s2 = s_lo + (rr - b2 * s_cnt);
        float4 v;
        v.x = acc[i][0] + bb.x; v.y = acc[i][1] + bb.y; v.z = acc[i][2] + bb.z; v.w = acc[i][3] + bb.w;
        *(float4*)(out + (size_t)(b2 * SDIM + s2) * DDIM + col0 + (tx << 2)) = v;
    }
}

extern "C" void kernel_launch(void* const* d_in, const int* in_sizes, int n_in,
                              void* d_out, int out_size, void* d_ws, size_t ws_size,
                              hipStream_t stream)
{
    const float* X  = (const float*)d_in[0];
    const float* W1 = (const float*)d_in[1];
    const float* b1 = (const float*)d_in[2];
    const float* W2 = (const float*)d_in[3];
    const float* b2 = (const float*)d_in[4];
    const float* W3 = (const float*)d_in[5];
    const float* b3 = (const float*)d_in[6];
    const float* W4 = (const float*)d_in[7];
    const float* b4 = (const float*)d_in[8];
    float* out = (float*)d_out;
    float* ws  = (float*)d_ws;

    prep_weights<<<dim3(512), dim3(256), 0, stream>>>(W1, b1, W2, b2, W3, b3, W4, b4, ws);

    // interior s in [2,256): M = 64*254 rows, K = 1536, window starts at s-2
    gemm_rows<<<dim3(254, 8), dim3(256), 0, stream>>>(X, ws + OFF_GINT, ws + OFF_BI, out, 2, 254, 1536, -2);
    // tail s in [256,512): unigram only, K = 256
    gemm_rows<<<dim3(256, 8), dim3(256), 0, stream>>>(X, W1, b1, out, 256, 256, 256, 0);
    // s = 0: K = 1024, window starts at 0
    gemm_rows<<<dim3(1, 8), dim3(256), 0, stream>>>(X, ws + OFF_G0, ws + OFF_B0, out, 0, 1, 1024, 0);
    // s = 1: K = 1280, window starts at 0 (dlo = -1)
    gemm_rows<<<dim3(1, 8), dim3(256), 0, stream>>>(X, ws + OFF_G1, ws + OFF_B1, out, 1, 1, 1280, -1);
}

// Round 2
// 230.245 us; speedup vs baseline: 3.0856x; 3.0856x over previous
//
#include <hip/hip_runtime.h>
#include <hip/hip_bf16.h>

// B=64, S=512, E=256, D=512
#define EDIM 256
#define SDIM 512
#define BDIM 64
#define DDIM 512
#define SPAD 514   // padded S rows per batch in Xp (2 zero rows at front)

// ws byte offsets
#define OFF_XP    0u           // bf16 [64][514][256]  = 16,842,752 B
#define OFF_GINTB 16842752u    // bf16 [512][1536]     =  1,572,864 B
#define OFF_W1B   18415616u    // bf16 [512][256]      =    262,144 B
#define OFF_G0T   18677760u    // f32  [1024][512]     =  2,097,152 B
#define OFF_G1T   20774912u    // f32  [1280][512]     =  2,621,440 B
#define OFF_BI    23396352u    // f32  [512]           =      2,048 B

typedef __attribute__((ext_vector_type(8))) __bf16 bf16x8;
typedef __attribute__((ext_vector_type(4))) float  f32x4;

__device__ __forceinline__ unsigned short f2bf(float f) {
    unsigned int u = __float_as_uint(f);
    u = (u + 0x7fffu + ((u >> 16) & 1u)) >> 16;   // RNE
    return (unsigned short)u;
}

// ---- Xp builder: bf16 copy of X with 2 zero rows prepended per batch ----
__global__ __launch_bounds__(256) void cvt_pad(const float* __restrict__ X,
                                               unsigned short* __restrict__ Xp)
{
    int i = blockIdx.x * 256 + threadIdx.x;       // quad index over 64*514*64
    const int row = i >> 6;                        // b*514 + j
    const int q   = i & 63;
    const int b   = row / SPAD;
    const int j   = row - b * SPAD;
    ushort4 v;
    if (j < 2) {
        v.x = v.y = v.z = v.w = 0;
    } else {
        const float4 f = *(const float4*)(X + ((size_t)(b * SDIM + j - 2)) * EDIM + q * 4);
        v.x = f2bf(f.x); v.y = f2bf(f.y); v.z = f2bf(f.z); v.w = f2bf(f.w);
    }
    *(ushort4*)(Xp + (size_t)row * EDIM + q * 4) = v;
}

// ---- combined-weight builder (see round-0 derivation comments) ----
__global__ __launch_bounds__(256) void prep_weights(
    const float* __restrict__ W1, const float* __restrict__ b1,
    const float* __restrict__ W2, const float* __restrict__ b2,
    const float* __restrict__ W3, const float* __restrict__ b3,
    const float* __restrict__ W4, const float* __restrict__ b4,
    char* __restrict__ wsb)
{
    const int d = blockIdx.x;    // 0..511
    const int e = threadIdx.x;   // 0..255
    const int de = d * EDIM + e;

    const float w1  = W1[de];
    const float w20 = W2[de * 2 + 0], w21 = W2[de * 2 + 1];
    const float w30 = W3[de * 3 + 0], w31 = W3[de * 3 + 1], w32 = W3[de * 3 + 2];
    const float w40 = W4[de * 4 + 0], w41 = W4[de * 4 + 1], w42 = W4[de * 4 + 2], w43 = W4[de * 4 + 3];

    // interior combined weights, bf16, [512][1536] (delta = -2..3)
    unsigned short* Gi = (unsigned short*)(wsb + OFF_GINTB) + (size_t)d * 1536;
    Gi[0 * EDIM + e] = f2bf(w40);
    Gi[1 * EDIM + e] = f2bf(w30 + w40 + w41);
    Gi[2 * EDIM + e] = f2bf(w1 + w20 + w30 + w31 + w40 + w41 + w42);
    Gi[3 * EDIM + e] = f2bf(w21 + w31 + w32 + w41 + w42 + w43);
    Gi[4 * EDIM + e] = f2bf(w32 + w42 + w43);
    Gi[5 * EDIM + e] = f2bf(w43);

    // unigram weights bf16 [512][256] for the tail GEMM
    ((unsigned short*)(wsb + OFF_W1B))[de] = f2bf(w1);

    // s=0 weights fp32, TRANSPOSED [1024][512]: G0t[k][d], k = tap*256+e
    float* G0t = (float*)(wsb + OFF_G0T);
    G0t[(0 * EDIM + e) * DDIM + d] = w1 + w20 + w30 + w40;
    G0t[(1 * EDIM + e) * DDIM + d] = w21 + w31 + w41;
    G0t[(2 * EDIM + e) * DDIM + d] = w32 + w42;
    G0t[(3 * EDIM + e) * DDIM + d] = w43;

    // s=1 weights fp32, TRANSPOSED [1280][512]
    float* G1t = (float*)(wsb + OFF_G1T);
    G1t[(0 * EDIM + e) * DDIM + d] = w30 + w40;
    G1t[(1 * EDIM + e) * DDIM + d] = w1 + w20 + w30 + w31 + w40 + w41;
    G1t[(2 * EDIM + e) * DDIM + d] = w21 + w31 + w32 + w41 + w42;
    G1t[(3 * EDIM + e) * DDIM + d] = w32 + w42 + w43;
    G1t[(4 * EDIM + e) * DDIM + d] = w43;

    if (e == 0)
        ((float*)(wsb + OFF_BI))[d] = b1[d] + b2[d] + 2.0f * b3[d] + 3.0f * b4[d];
}

// ---- bf16 MFMA GEMM, m97-style: 128x128 tile, BK=32, 256 thr = 4 waves (2x2),
//      each wave 4x4 tiles of 16x16x32. A rows come from padded Xp; B is
//      Gbf[DDIM][K] row-major (gemm_bt). Row r -> (b = r>>8, s = s_lo + (r&255)),
//      A-row = Xp + (b*514 + s_lo + (r&255) + aoff)*256 elems, K contiguous bf16.
__global__ __launch_bounds__(256) void gemm_mfma(
    const unsigned short* __restrict__ Xp,
    const unsigned short* __restrict__ Gbf,
    const float* __restrict__ bias,
    float* __restrict__ out,
    int s_lo, int K, int aoff)
{
    __shared__ __align__(16) unsigned short Alds[128 * 32];
    __shared__ __align__(16) unsigned short Blds[128 * 32];

    const int tid  = threadIdx.x;
    const int w    = tid >> 6;
    const int l    = tid & 63;
    const int row0 = blockIdx.x * 128;
    const int col0 = blockIdx.y * 128;

    // --- staging: wave w stages chunks {2w, 2w+1} of A and B (16 rows/chunk) ---
    const int sub = l >> 2;             // row within chunk
    const int kb  = (l & 3) * 16;       // byte offset within row's K-slice

    const int ra0 = row0 + 32 * w + sub;
    const int ra1 = ra0 + 16;
    const int ba0 = ra0 >> 8, sa0 = ra0 & 255;
    const int ba1 = ra1 >> 8, sa1 = ra1 & 255;
    const char* ga0 = (const char*)(Xp + ((size_t)(ba0 * SPAD + s_lo + sa0 + aoff)) * EDIM) + kb;
    const char* ga1 = (const char*)(Xp + ((size_t)(ba1 * SPAD + s_lo + sa1 + aoff)) * EDIM) + kb;
    const char* gb0 = (const char*)(Gbf + (size_t)(col0 + 32 * w + sub) * K) + kb;
    const char* gb1 = (const char*)(Gbf + (size_t)(col0 + 32 * w + 16 + sub) * K) + kb;

    // wave-uniform LDS chunk bases (lane i lands at base + i*16 B)
    unsigned short* la0 = Alds + (32 * w) * 32;
    unsigned short* la1 = Alds + (32 * w + 16) * 32;
    unsigned short* lb0 = Blds + (32 * w) * 32;
    unsigned short* lb1 = Blds + (32 * w + 16) * 32;

    // --- fragment read coords ---
    const int wr  = (w >> 1) * 64;
    const int wc  = (w & 1) * 64;
    const int fm  = l & 15;
    const int fkb = (l >> 4) * 16;      // byte offset of this lane's 8 bf16 along k

    f32x4 acc[4][4] = {};

    const char* Ab = (const char*)Alds;
    const char* Bb = (const char*)Blds;

    const int nk = K >> 5;
    for (int kt = 0; kt < nk; ++kt) {
        __syncthreads();   // prior iter's ds_reads done before overwrite
        __builtin_amdgcn_global_load_lds((const __attribute__((address_space(1))) void*)ga0,
                                         (__attribute__((address_space(3))) void*)la0, 16, 0, 0);
        __builtin_amdgcn_global_load_lds((const __attribute__((address_space(1))) void*)ga1,
                                         (__attribute__((address_space(3))) void*)la1, 16, 0, 0);
        __builtin_amdgcn_global_load_lds((const __attribute__((address_space(1))) void*)gb0,
                                         (__attribute__((address_space(3))) void*)lb0, 16, 0, 0);
        __builtin_amdgcn_global_load_lds((const __attribute__((address_space(1))) void*)gb1,
                                         (__attribute__((address_space(3))) void*)lb1, 16, 0, 0);
        ga0 += 64; ga1 += 64; gb0 += 64; gb1 += 64;
        __syncthreads();   // staged data visible

        bf16x8 af[4], bfr[4];
#pragma unroll
        for (int t = 0; t < 4; ++t) {
            af[t]  = *(const bf16x8*)(Ab + (wr + t * 16 + fm) * 64 + fkb);
            bfr[t] = *(const bf16x8*)(Bb + (wc + t * 16 + fm) * 64 + fkb);
        }
#pragma unroll
        for (int i = 0; i < 4; ++i)
#pragma unroll
            for (int j = 0; j < 4; ++j)
                acc[i][j] = __builtin_amdgcn_mfma_f32_16x16x32_bf16(af[i], bfr[j], acc[i][j], 0, 0, 0);
    }

    // --- epilogue: C/D layout col = lane&15, row = (lane>>4)*4 + reg ---
    const int ocol = col0 + wc + fm;
    const int rq   = (l >> 4) * 4;
    float bv[4];
#pragma unroll
    for (int j = 0; j < 4; ++j) bv[j] = bias[ocol + j * 16];

#pragma unroll
    for (int i = 0; i < 4; ++i) {
#pragma unroll
        for (int r = 0; r < 4; ++r) {
            const int rr = row0 + wr + i * 16 + rq + r;
            const int bb = rr >> 8;
            const int ss = s_lo + (rr & 255);
            float* op = out + ((size_t)(bb * SDIM + ss)) * DDIM + ocol;
#pragma unroll
            for (int j = 0; j < 4; ++j)
                op[j * 16] = acc[i][j][r] + bv[j];
        }
    }
}

// ---- exact fp32 rewrite of s=0 and s=1 (overwrites the padded-GEMM values) ----
__global__ __launch_bounds__(512) void edge_fix(
    const float* __restrict__ X, const char* __restrict__ wsb,
    const float* __restrict__ b1, const float* __restrict__ b2,
    const float* __restrict__ b3, const float* __restrict__ b4,
    float* __restrict__ out)
{
    const int b = blockIdx.x;      // 0..63
    const int d = threadIdx.x;     // 0..511 (output column)
    __shared__ float xs[1280];
    for (int i = threadIdx.x; i < 1280; i += 512)
        xs[i] = X[(size_t)b * SDIM * EDIM + i];
    __syncthreads();

    const float* G0t = (const float*)(wsb + OFF_G0T);   // [1024][512]
    const float* G1t = (const float*)(wsb + OFF_G1T);   // [1280][512]

    float a0 = 0.f, a1 = 0.f;
    for (int k = 0; k < 1024; ++k) {
        const float x = xs[k];
        a0 += x * G0t[(size_t)k * DDIM + d];
        a1 += x * G1t[(size_t)k * DDIM + d];
    }
    for (int k = 1024; k < 1280; ++k)
        a1 += xs[k] * G1t[(size_t)k * DDIM + d];

    out[((size_t)b * SDIM + 0) * DDIM + d] = a0 + b1[d] + b2[d] + b3[d] + b4[d];
    out[((size_t)b * SDIM + 1) * DDIM + d] = a1 + b1[d] + b2[d] + 2.f * b3[d] + 2.f * b4[d];
}

extern "C" void kernel_launch(void* const* d_in, const int* in_sizes, int n_in,
                              void* d_out, int out_size, void* d_ws, size_t ws_size,
                              hipStream_t stream)
{
    const float* X  = (const float*)d_in[0];
    const float* W1 = (const float*)d_in[1];
    const float* b1 = (const float*)d_in[2];
    const float* W2 = (const float*)d_in[3];
    const float* b2 = (const float*)d_in[4];
    const float* W3 = (const float*)d_in[5];
    const float* b3 = (const float*)d_in[6];
    const float* W4 = (const float*)d_in[7];
    const float* b4 = (const float*)d_in[8];
    float* out = (float*)d_out;
    char*  wsb = (char*)d_ws;

    unsigned short* Xp = (unsigned short*)(wsb + OFF_XP);

    // 64*514*64 quads / 256 threads
    cvt_pad<<<dim3(BDIM * SPAD * 64 / 256), dim3(256), 0, stream>>>(X, Xp);
    prep_weights<<<dim3(512), dim3(256), 0, stream>>>(W1, b1, W2, b2, W3, b3, W4, b4, wsb);

    // interior: s in [0,256) with combined weights; s=0,1 fixed up afterwards.
    // M = 64*256 = 16384 rows = 128 tiles; N = 512 = 4 tiles; K = 1536.
    gemm_mfma<<<dim3(128, 4), dim3(256), 0, stream>>>(
        Xp, (const unsigned short*)(wsb + OFF_GINTB), (const float*)(wsb + OFF_BI),
        out, 0, 1536, 0);

    // tail: s in [256,512), unigram only, K = 256 (A-row = Xp row s+2)
    gemm_mfma<<<dim3(128, 4), dim3(256), 0, stream>>>(
        Xp, (const unsigned short*)(wsb + OFF_W1B), b1,
        out, 256, 256, 2);

    // exact fp32 overwrite of s=0,1
    edge_fix<<<dim3(BDIM), dim3(512), 0, stream>>>(X, wsb, b1, b2, b3, b4, out);
}

// Round 3
// 188.226 us; speedup vs baseline: 3.7744x; 1.2232x over previous
//
#include <hip/hip_runtime.h>
#include <hip/hip_bf16.h>

// B=64, S=512, E=256, D=512
#define EDIM 256
#define SDIM 512
#define BDIM 64
#define DDIM 512
#define SPAD 514   // padded S rows per batch in Xp (2 zero rows at front)

// ws byte offsets
#define OFF_XP    0u           // bf16 [64][514][256]  = 16,842,752 B
#define OFF_GINTB 16842752u    // bf16 [512][1536]     =  1,572,864 B
#define OFF_W1B   18415616u    // bf16 [512][256]      =    262,144 B
#define OFF_G0T   18677760u    // f32  [1024][512]     =  2,097,152 B
#define OFF_G1T   20774912u    // f32  [1280][512]     =  2,621,440 B
#define OFF_BI    23396352u    // f32  [512]           =      2,048 B

typedef __attribute__((ext_vector_type(8))) __bf16 bf16x8;
typedef __attribute__((ext_vector_type(4))) float  f32x4;

__device__ __forceinline__ unsigned short f2bf(float f) {
    unsigned int u = __float_as_uint(f);
    u = (u + 0x7fffu + ((u >> 16) & 1u)) >> 16;   // RNE
    return (unsigned short)u;
}

// ============ launch 1: cvt_pad (blocks 0..8223) + prep_weights (8224..8735) ============
__global__ __launch_bounds__(256) void prep_all(
    const float* __restrict__ X,
    const float* __restrict__ W1, const float* __restrict__ b1,
    const float* __restrict__ W2, const float* __restrict__ b2,
    const float* __restrict__ W3, const float* __restrict__ b3,
    const float* __restrict__ W4, const float* __restrict__ b4,
    char* __restrict__ wsb)
{
    if (blockIdx.x < 8224) {
        // ---- bf16 copy of X with 2 zero rows prepended per batch ----
        unsigned short* Xp = (unsigned short*)(wsb + OFF_XP);
        int i = blockIdx.x * 256 + threadIdx.x;   // quad index over 64*514*64
        const int row = i >> 6;                    // b*514 + j
        const int q   = i & 63;
        const int b   = row / SPAD;
        const int j   = row - b * SPAD;
        ushort4 v;
        if (j < 2) {
            v.x = v.y = v.z = v.w = 0;
        } else {
            const float4 f = *(const float4*)(X + ((size_t)(b * SDIM + j - 2)) * EDIM + q * 4);
            v.x = f2bf(f.x); v.y = f2bf(f.y); v.z = f2bf(f.z); v.w = f2bf(f.w);
        }
        *(ushort4*)(Xp + (size_t)row * EDIM + q * 4) = v;
        return;
    }

    // ---- combined-weight builder (delta-grouping derivation, see R0 notes) ----
    const int d = blockIdx.x - 8224;   // 0..511
    const int e = threadIdx.x;         // 0..255
    const int de = d * EDIM + e;

    const float w1  = W1[de];
    const float w20 = W2[de * 2 + 0], w21 = W2[de * 2 + 1];
    const float w30 = W3[de * 3 + 0], w31 = W3[de * 3 + 1], w32 = W3[de * 3 + 2];
    const float w40 = W4[de * 4 + 0], w41 = W4[de * 4 + 1], w42 = W4[de * 4 + 2], w43 = W4[de * 4 + 3];

    unsigned short* Gi = (unsigned short*)(wsb + OFF_GINTB) + (size_t)d * 1536;
    Gi[0 * EDIM + e] = f2bf(w40);
    Gi[1 * EDIM + e] = f2bf(w30 + w40 + w41);
    Gi[2 * EDIM + e] = f2bf(w1 + w20 + w30 + w31 + w40 + w41 + w42);
    Gi[3 * EDIM + e] = f2bf(w21 + w31 + w32 + w41 + w42 + w43);
    Gi[4 * EDIM + e] = f2bf(w32 + w42 + w43);
    Gi[5 * EDIM + e] = f2bf(w43);

    ((unsigned short*)(wsb + OFF_W1B))[de] = f2bf(w1);

    // s=0 / s=1 exact fp32 weights, transposed [K][512] for coalesced k-loops
    float* G0t = (float*)(wsb + OFF_G0T);
    G0t[(0 * EDIM + e) * DDIM + d] = w1 + w20 + w30 + w40;
    G0t[(1 * EDIM + e) * DDIM + d] = w21 + w31 + w41;
    G0t[(2 * EDIM + e) * DDIM + d] = w32 + w42;
    G0t[(3 * EDIM + e) * DDIM + d] = w43;

    float* G1t = (float*)(wsb + OFF_G1T);
    G1t[(0 * EDIM + e) * DDIM + d] = w30 + w40;
    G1t[(1 * EDIM + e) * DDIM + d] = w1 + w20 + w30 + w31 + w40 + w41;
    G1t[(2 * EDIM + e) * DDIM + d] = w21 + w31 + w32 + w41 + w42;
    G1t[(3 * EDIM + e) * DDIM + d] = w32 + w42 + w43;
    G1t[(4 * EDIM + e) * DDIM + d] = w43;

    if (e == 0)
        ((float*)(wsb + OFF_BI))[d] = b1[d] + b2[d] + 2.0f * b3[d] + 3.0f * b4[d];
}

// ============ launch 2: mega kernel ============
// blocks [0,512):    interior GEMM, s in [0,256), K=1536 (skips stores at s<2)
// blocks [512,1024): tail GEMM,     s in [256,512), K=256
// blocks [1024,1280): exact fp32 fix of s=0,1 (owns those output rows)
__global__ __launch_bounds__(256) void mega(
    const unsigned short* __restrict__ Xp,
    const char* __restrict__ wsb,
    const float* __restrict__ X,
    const float* __restrict__ b1, const float* __restrict__ b2,
    const float* __restrict__ b3, const float* __restrict__ b4,
    float* __restrict__ out)
{
    __shared__ __align__(16) char smem[16384];
    const int id  = blockIdx.x;
    const int tid = threadIdx.x;

    if (id >= 1024) {
        // ---------------- edge path: exact fp32 for s=0,1 ----------------
        const int e  = id - 1024;         // 0..255
        const int b0 = (e >> 3) * 2;      // 2 batches per block
        const int dg = (e & 7) * 64;      // 64 d-columns per block
        float* xs = (float*)smem;         // [2][1280]
        float* pa = (float*)(smem + 10240); // [4 ks][4 combo][64 dl]

        for (int i = tid; i < 2560; i += 256) {
            const int bb = (i < 1280) ? 0 : 1;
            const int kk = i - bb * 1280;
            xs[i] = X[(size_t)(b0 + bb) * (SDIM * EDIM) + kk];
        }
        __syncthreads();

        const float* G0t = (const float*)(wsb + OFF_G0T);   // [1024][512]
        const float* G1t = (const float*)(wsb + OFF_G1T);   // [1280][512]

        const int dl = tid & 63, ks = tid >> 6;
        const int d  = dg + dl;

        float a00 = 0.f, a10 = 0.f;   // s=0, batch 0/1
        float a01 = 0.f, a11 = 0.f;   // s=1, batch 0/1
#pragma unroll 4
        for (int k = ks * 256; k < ks * 256 + 256; ++k) {
            const float g = G0t[(size_t)k * DDIM + d];
            a00 += g * xs[k]; a10 += g * xs[1280 + k];
        }
#pragma unroll 4
        for (int k = ks * 320; k < ks * 320 + 320; ++k) {
            const float g = G1t[(size_t)k * DDIM + d];
            a01 += g * xs[k]; a11 += g * xs[1280 + k];
        }
        pa[(ks * 4 + 0) * 64 + dl] = a00;
        pa[(ks * 4 + 1) * 64 + dl] = a01;
        pa[(ks * 4 + 2) * 64 + dl] = a10;
        pa[(ks * 4 + 3) * 64 + dl] = a11;
        __syncthreads();

        // final reduce: thread -> (combo = tid>>6, dl = tid&63)
        const int c  = tid >> 6;          // batch*2 + s
        const int dl2 = tid & 63;
        const int d2  = dg + dl2;
        float v = pa[(0 * 4 + c) * 64 + dl2] + pa[(1 * 4 + c) * 64 + dl2]
                + pa[(2 * 4 + c) * 64 + dl2] + pa[(3 * 4 + c) * 64 + dl2];
        const int s  = c & 1;
        const int bb = b0 + (c >> 1);
        const float bs = (s == 0) ? (b1[d2] + b2[d2] + b3[d2] + b4[d2])
                                  : (b1[d2] + b2[d2] + 2.f * b3[d2] + 2.f * b4[d2]);
        out[((size_t)bb * SDIM + s) * DDIM + d2] = v + bs;
        return;
    }

    // ---------------- GEMM path (m97 structure) ----------------
    const bool is_tail = id >= 512;
    const int  idx  = is_tail ? id - 512 : id;
    const int  row0 = (idx & 127) * 128;
    const int  col0 = (idx >> 7) * 128;
    const int  K     = is_tail ? 256 : 1536;
    const int  s_lo  = is_tail ? 256 : 0;
    const int  aoff  = is_tail ? 2 : 0;
    const unsigned short* Gbf = is_tail ? (const unsigned short*)(wsb + OFF_W1B)
                                        : (const unsigned short*)(wsb + OFF_GINTB);
    const float* bias = is_tail ? b1 : (const float*)(wsb + OFF_BI);

    unsigned short* Alds = (unsigned short*)smem;             // [128][32]
    unsigned short* Blds = (unsigned short*)(smem + 8192);    // [128][32]

    const int w = tid >> 6;
    const int l = tid & 63;

    // staging: wave w stages chunks {2w,2w+1} of A and B (16 rows x 64 B each)
    const int sub = l >> 2;
    const int kb  = (l & 3) * 16;

    const int ra0 = row0 + 32 * w + sub;
    const int ra1 = ra0 + 16;
    const int ba0 = ra0 >> 8, sa0 = ra0 & 255;
    const int ba1 = ra1 >> 8, sa1 = ra1 & 255;
    const char* ga0 = (const char*)(Xp + ((size_t)(ba0 * SPAD + s_lo + sa0 + aoff)) * EDIM) + kb;
    const char* ga1 = (const char*)(Xp + ((size_t)(ba1 * SPAD + s_lo + sa1 + aoff)) * EDIM) + kb;
    const char* gb0 = (const char*)(Gbf + (size_t)(col0 + 32 * w + sub) * K) + kb;
    const char* gb1 = (const char*)(Gbf + (size_t)(col0 + 32 * w + 16 + sub) * K) + kb;

    unsigned short* la0 = Alds + (32 * w) * 32;
    unsigned short* la1 = Alds + (32 * w + 16) * 32;
    unsigned short* lb0 = Blds + (32 * w) * 32;
    unsigned short* lb1 = Blds + (32 * w + 16) * 32;

    const int wr  = (w >> 1) * 64;
    const int wc  = (w & 1) * 64;
    const int fm  = l & 15;
    const int fkb = (l >> 4) * 16;

    f32x4 acc[4][4] = {};
    const char* Ab = (const char*)Alds;
    const char* Bb = (const char*)Blds;

    const int nk = K >> 5;
    for (int kt = 0; kt < nk; ++kt) {
        __syncthreads();
        __builtin_amdgcn_global_load_lds((const __attribute__((address_space(1))) void*)ga0,
                                         (__attribute__((address_space(3))) void*)la0, 16, 0, 0);
        __builtin_amdgcn_global_load_lds((const __attribute__((address_space(1))) void*)ga1,
                                         (__attribute__((address_space(3))) void*)la1, 16, 0, 0);
        __builtin_amdgcn_global_load_lds((const __attribute__((address_space(1))) void*)gb0,
                                         (__attribute__((address_space(3))) void*)lb0, 16, 0, 0);
        __builtin_amdgcn_global_load_lds((const __attribute__((address_space(1))) void*)gb1,
                                         (__attribute__((address_space(3))) void*)lb1, 16, 0, 0);
        ga0 += 64; ga1 += 64; gb0 += 64; gb1 += 64;
        __syncthreads();

        bf16x8 af[4], bfr[4];
#pragma unroll
        for (int t = 0; t < 4; ++t) {
            af[t]  = *(const bf16x8*)(Ab + (wr + t * 16 + fm) * 64 + fkb);
            bfr[t] = *(const bf16x8*)(Bb + (wc + t * 16 + fm) * 64 + fkb);
        }
#pragma unroll
        for (int i = 0; i < 4; ++i)
#pragma unroll
            for (int j = 0; j < 4; ++j)
                acc[i][j] = __builtin_amdgcn_mfma_f32_16x16x32_bf16(af[i], bfr[j], acc[i][j], 0, 0, 0);
    }

    // epilogue: C/D layout col = lane&15, row = (lane>>4)*4 + reg
    const int ocol = col0 + wc + fm;
    const int rq   = (l >> 4) * 4;
    float bv[4];
#pragma unroll
    for (int j = 0; j < 4; ++j) bv[j] = bias[ocol + j * 16];

#pragma unroll
    for (int i = 0; i < 4; ++i) {
#pragma unroll
        for (int r = 0; r < 4; ++r) {
            const int rr = row0 + wr + i * 16 + rq + r;
            const int ssl = rr & 255;
            if (!is_tail && ssl < 2) continue;   // s=0,1 owned by edge path
            const int bb = rr >> 8;
            const int ss = s_lo + ssl;
            float* op = out + ((size_t)(bb * SDIM + ss)) * DDIM + ocol;
#pragma unroll
            for (int j = 0; j < 4; ++j)
                op[j * 16] = acc[i][j][r] + bv[j];
        }
    }
}

extern "C" void kernel_launch(void* const* d_in, const int* in_sizes, int n_in,
                              void* d_out, int out_size, void* d_ws, size_t ws_size,
                              hipStream_t stream)
{
    const float* X  = (const float*)d_in[0];
    const float* W1 = (const float*)d_in[1];
    const float* b1 = (const float*)d_in[2];
    const float* W2 = (const float*)d_in[3];
    const float* b2 = (const float*)d_in[4];
    const float* W3 = (const float*)d_in[5];
    const float* b3 = (const float*)d_in[6];
    const float* W4 = (const float*)d_in[7];
    const float* b4 = (const float*)d_in[8];
    float* out = (float*)d_out;
    char*  wsb = (char*)d_ws;

    // launch 1: cvt_pad (8224 blocks) + prep_weights (512 blocks)
    prep_all<<<dim3(8736), dim3(256), 0, stream>>>(X, W1, b1, W2, b2, W3, b3, W4, b4, wsb);

    // launch 2: interior GEMM + tail GEMM + s=0,1 exact fix, one grid
    mega<<<dim3(1280), dim3(256), 0, stream>>>(
        (const unsigned short*)(wsb + OFF_XP), wsb, X, b1, b2, b3, b4, out);
}